// Round 8
// baseline (917.443 us; speedup 1.0000x reference)
//
#include <hip/hip_runtime.h>
#include <hip/hip_fp16.h>

constexpr int IN_DIM  = 256;
constexpr int HID_DIM = 128;
constexpr int OUT_DIM = 64;

typedef _Float16 half8 __attribute__((ext_vector_type(8)));
typedef float floatx4 __attribute__((ext_vector_type(4)));

// ---------------- CSR build via direct scatter (replaces counting sort) ----------------
// Sorted col order is unnecessary: row sums are commutative, and rows need not be
// laid out in node order. deg -> per-node base alloc (wave-coalesced atomic) -> scatter.

__global__ __launch_bounds__(256) void k_deg(const int* __restrict__ dst, int E,
                                             int* __restrict__ deg) {
  const int stride = gridDim.x * 256;
  for (int e = blockIdx.x * 256 + threadIdx.x; e < E; e += stride) {
    int d = __builtin_nontemporal_load(&dst[e]);
    atomicAdd(&deg[d], 1);
  }
}

__global__ __launch_bounds__(256) void k_alloc(const int* __restrict__ deg, int N,
                                               int* __restrict__ tot,
                                               int* __restrict__ rowbeg,
                                               int* __restrict__ cur,
                                               float* __restrict__ dis) {
  const int v = blockIdx.x * 256 + threadIdx.x;
  const int lane = threadIdx.x & 63;
  int d = (v < N) ? deg[v] : 0;
  // wave inclusive scan of d
  int inc = d;
#pragma unroll
  for (int off = 1; off < 64; off <<= 1) {
    int t = __shfl_up(inc, off);
    if (lane >= off) inc += t;
  }
  int wtot = __shfl(inc, 63);
  int base = 0;
  if (lane == 63) base = atomicAdd(tot, wtot);   // one atomic per wave
  base = __shfl(base, 63) + (inc - d);           // exclusive prefix within wave
  if (v < N) {
    rowbeg[v] = base;
    cur[v] = base;
    dis[v] = rsqrtf((float)d + 1.0f);            // +1 self loop
  }
}

__global__ __launch_bounds__(256) void k_scat(const int* __restrict__ src,
                                              const int* __restrict__ dst, int E,
                                              int* __restrict__ cur,
                                              int* __restrict__ col) {
  const int stride = gridDim.x * 256;
  for (int e = blockIdx.x * 256 + threadIdx.x; e < E; e += stride) {
    int d = __builtin_nontemporal_load(&dst[e]);
    int s = __builtin_nontemporal_load(&src[e]);
    int p = atomicAdd(&cur[d], 1);
    col[p] = s;
  }
}

// ---------------- W pre-pack into MFMA B-fragment order (fp16) ----------------
// B-frag for 16x16x32_f16: lane holds B[k = (lane>>4)*8 + j][n = lane&15].
// Wp flat index: ((ct*(K/32) + ks)*64 + lane)*8 + j, ct = n>>4, ks = k>>5.

template <int K, int N>
__device__ inline void packW_one(const float* __restrict__ W, _Float16* __restrict__ Wp,
                                 int idx) {
  int k = idx / N, n = idx % N;
  int ct = n >> 4, ks = k >> 5, q = (k >> 3) & 3, j = k & 7;
  int lane = (n & 15) + (q << 4);
  Wp[((((size_t)ct * (K / 32) + ks) * 64 + lane) << 3) + j] = (_Float16)W[idx];
}

__global__ __launch_bounds__(256) void k_packAll(const float* __restrict__ W1, _Float16* __restrict__ Wp1,
                                                 const float* __restrict__ W2, _Float16* __restrict__ Wp2,
                                                 const float* __restrict__ W3, _Float16* __restrict__ Wp3) {
  constexpr int S1 = IN_DIM * HID_DIM;            // 32768
  constexpr int S2 = S1 + HID_DIM * HID_DIM;      // 49152
  constexpr int S3 = S2 + HID_DIM * OUT_DIM;      // 57344
  int idx = blockIdx.x * 256 + threadIdx.x;
  if (idx < S1) packW_one<IN_DIM, HID_DIM>(W1, Wp1, idx);
  else if (idx < S2) packW_one<HID_DIM, HID_DIM>(W2, Wp2, idx - S1);
  else if (idx < S3) packW_one<HID_DIM, OUT_DIM>(W3, Wp3, idx - S2);
}

// ---------------- MFMA GEMM: out[r][c] = fp16(dis[r] * sum_k A[r][k]*W[k][c]) --------
// r5-proven form (r7's 8-wave grid-stride variant spilled: WRITE 25->224 MB scratch).
// Block = 4 waves; wave w computes rows [blk*64 + w*16, +16) x all N cols.
// Wp staged in LDS per block, K split into <=32KB halves.

template <int K, int N, typename AT>
__global__ __launch_bounds__(256) void k_gemm_mfma(const AT* __restrict__ A,
                                                   const _Float16* __restrict__ Wp,
                                                   const float* __restrict__ dis,
                                                   __half* __restrict__ out, int M) {
  constexpr int CT = N / 16;   // 16-col tiles
  constexpr int KS = K / 32;   // 32-k steps
  constexpr int KH = (K * N * 2 > 32768) ? 2 : 1;  // k-halves for staging
  constexpr int KSH = KS / KH;                     // ks per half
  constexpr int NF4 = CT * KSH * 64;               // float4s staged per half (<=2048)
  __shared__ float4 wlds[NF4];                     // <=32 KB

  const int wave = threadIdx.x >> 6, lane = threadIdx.x & 63;
  const int q = lane >> 4, mlane = lane & 15;
  const int row0 = blockIdx.x * 64 + wave * 16;
  int arow = row0 + mlane;
  if (arow > M - 1) arow = M - 1;  // clamp (dup row, stores guarded)

  const float4* __restrict__ wsrc = (const float4*)Wp;

  floatx4 acc[CT];
#pragma unroll
  for (int c = 0; c < CT; c++) acc[c] = (floatx4){0.f, 0.f, 0.f, 0.f};

#pragma unroll
  for (int h = 0; h < KH; h++) {
    if (h) __syncthreads();  // all waves done reading previous half
#pragma unroll
    for (int i = threadIdx.x; i < NF4; i += 256) {
      int c = i / (KSH * 64);
      int rem = i & (KSH * 64 - 1);
      wlds[i] = wsrc[(size_t)(c * KS + h * KSH) * 64 + rem];
    }
    __syncthreads();

#pragma unroll
    for (int ksl = 0; ksl < KSH; ksl++) {
      const int ks = h * KSH + ksl;
      half8 a;
      if constexpr (sizeof(AT) == 4) {
        const float* ap = &A[(size_t)arow * K + ks * 32 + q * 8];
        float4 f0 = *(const float4*)ap;
        float4 f1 = *(const float4*)(ap + 4);
        a[0] = (_Float16)f0.x; a[1] = (_Float16)f0.y;
        a[2] = (_Float16)f0.z; a[3] = (_Float16)f0.w;
        a[4] = (_Float16)f1.x; a[5] = (_Float16)f1.y;
        a[6] = (_Float16)f1.z; a[7] = (_Float16)f1.w;
      } else {
        a = *(const half8*)&A[(size_t)arow * K + ks * 32 + q * 8];
      }
#pragma unroll
      for (int c = 0; c < CT; c++) {
        half8 b = *(const half8*)&wlds[(c * KSH + ksl) * 64 + lane];
        acc[c] = __builtin_amdgcn_mfma_f32_16x16x32_f16(a, b, acc[c], 0, 0, 0);
      }
    }
  }

  float dv[4]; int orow[4];
#pragma unroll
  for (int r = 0; r < 4; r++) {
    orow[r] = row0 + q * 4 + r;
    dv[r] = (orow[r] < M) ? dis[orow[r]] : 0.f;
  }
#pragma unroll
  for (int c = 0; c < CT; c++) {
    int cl = c * 16 + mlane;
#pragma unroll
    for (int r = 0; r < 4; r++)
      if (orow[r] < M)
        out[(size_t)orow[r] * N + cl] = __float2half_rn(dv[r] * acc[c][r]);
  }
}

// ---------------- aggregation F=128, quad-gather + shfl-distributed col ----------------
// One wave per node; lane = (r = lane>>4 neighbor-in-quad, c = lane&15 16B chunk).
// Col indices: ONE 64-wide VMEM load per 64 neighbors, __shfl distributes (LDS pipe).
// Rows addressed via rowbeg/deg (scatter CSR); order within row irrelevant.

template <bool RELU>
__global__ __launch_bounds__(256) void k_agg128(const __half* __restrict__ g,
                                                const int* __restrict__ rowbeg,
                                                const int* __restrict__ deg,
                                                const int* __restrict__ col,
                                                const float* __restrict__ dis,
                                                const float* __restrict__ bias,
                                                __half* __restrict__ out, int n, int v0) {
  const int lane = threadIdx.x & 63;
  const int r = lane >> 4;          // 0..3
  const int c = lane & 15;          // 0..15
  const int v = v0 + blockIdx.x * 4 + (threadIdx.x >> 6);
  if (v >= n) return;
  int p = rowbeg[v];
  int end = p + deg[v];
  const float dv = dis[v];

  float acc[8];
#pragma unroll
  for (int i = 0; i < 8; i++) acc[i] = 0.f;
  if (r == 0) {  // self term, counted once
    half8 s = *(const half8*)&g[(size_t)v * 128 + c * 8];
#pragma unroll
    for (int i = 0; i < 8; i++) acc[i] += (float)s[i];
  }

  while (p < end) {
    int navail = end - p;
    if (navail > 64) navail = 64;
    int cv = __builtin_nontemporal_load(&col[p + (lane < navail ? lane : 0)]);
    int done = 0;
    while (navail - done >= 8) {  // two quad-gathers in flight
      int u0 = __shfl(cv, done + r);
      int u1 = __shfl(cv, done + 4 + r);
      half8 t0 = *(const half8*)&g[(size_t)u0 * 128 + c * 8];
      half8 t1 = *(const half8*)&g[(size_t)u1 * 128 + c * 8];
#pragma unroll
      for (int i = 0; i < 8; i++) acc[i] += (float)t0[i];
#pragma unroll
      for (int i = 0; i < 8; i++) acc[i] += (float)t1[i];
      done += 8;
    }
    int remn = navail - done;  // 0..7
    if (remn > 0) {
      int m0 = remn < 4 ? remn : 4;
      int u0 = __shfl(cv, done + (r < m0 ? r : 0));
      half8 t0 = *(const half8*)&g[(size_t)u0 * 128 + c * 8];
      float k0 = (r < m0) ? 1.f : 0.f;
#pragma unroll
      for (int i = 0; i < 8; i++) acc[i] = fmaf(k0, (float)t0[i], acc[i]);
      if (remn > 4) {
        int m1 = remn - 4;
        int u1 = __shfl(cv, done + 4 + (r < m1 ? r : 0));
        half8 t1 = *(const half8*)&g[(size_t)u1 * 128 + c * 8];
        float k1 = (r < m1) ? 1.f : 0.f;
#pragma unroll
        for (int i = 0; i < 8; i++) acc[i] = fmaf(k1, (float)t1[i], acc[i]);
      }
    }
    p += navail;
  }

  // merge the 4 row-groups (lanes c, c+16, c+32, c+48)
#pragma unroll
  for (int i = 0; i < 8; i++) {
    acc[i] += __shfl_xor(acc[i], 16);
    acc[i] += __shfl_xor(acc[i], 32);
  }

  if (r == 0) {
    half8 h;
#pragma unroll
    for (int i = 0; i < 8; i++) {
      float o = fmaf(dv, acc[i], bias[c * 8 + i]);
      if (RELU) o = fmaxf(o, 0.f);
      h[i] = (_Float16)o;
    }
    *(half8*)&out[(size_t)v * 128 + c * 8] = h;
  }
}

// ---------------- aggregation F=64, oct-gather + shfl-distributed col ----------------

__global__ __launch_bounds__(256) void k_agg64(const __half* __restrict__ g,
                                               const int* __restrict__ rowbeg,
                                               const int* __restrict__ deg,
                                               const int* __restrict__ col,
                                               const float* __restrict__ dis,
                                               const float* __restrict__ bias,
                                               float* __restrict__ out, int n) {
  const int lane = threadIdx.x & 63;
  const int r = lane >> 3;          // 0..7
  const int c = lane & 7;           // 0..7
  const int v = blockIdx.x * 4 + (threadIdx.x >> 6);
  if (v >= n) return;
  int p = rowbeg[v];
  int end = p + deg[v];
  const float dv = dis[v];

  float acc[8];
#pragma unroll
  for (int i = 0; i < 8; i++) acc[i] = 0.f;
  if (r == 0) {
    half8 s = *(const half8*)&g[(size_t)v * 64 + c * 8];
#pragma unroll
    for (int i = 0; i < 8; i++) acc[i] += (float)s[i];
  }

  while (p < end) {
    int navail = end - p;
    if (navail > 64) navail = 64;
    int cv = __builtin_nontemporal_load(&col[p + (lane < navail ? lane : 0)]);
    int done = 0;
    while (navail - done >= 16) {  // two oct-gathers in flight
      int u0 = __shfl(cv, done + r);
      int u1 = __shfl(cv, done + 8 + r);
      half8 t0 = *(const half8*)&g[(size_t)u0 * 64 + c * 8];
      half8 t1 = *(const half8*)&g[(size_t)u1 * 64 + c * 8];
#pragma unroll
      for (int i = 0; i < 8; i++) acc[i] += (float)t0[i];
#pragma unroll
      for (int i = 0; i < 8; i++) acc[i] += (float)t1[i];
      done += 16;
    }
    int remn = navail - done;  // 0..15
    if (remn > 0) {
      int m0 = remn < 8 ? remn : 8;
      int u0 = __shfl(cv, done + (r < m0 ? r : 0));
      half8 t0 = *(const half8*)&g[(size_t)u0 * 64 + c * 8];
      float k0 = (r < m0) ? 1.f : 0.f;
#pragma unroll
      for (int i = 0; i < 8; i++) acc[i] = fmaf(k0, (float)t0[i], acc[i]);
      if (remn > 8) {
        int m1 = remn - 8;
        int u1 = __shfl(cv, done + 8 + (r < m1 ? r : 0));
        half8 t1 = *(const half8*)&g[(size_t)u1 * 64 + c * 8];
        float k1 = (r < m1) ? 1.f : 0.f;
#pragma unroll
        for (int i = 0; i < 8; i++) acc[i] = fmaf(k1, (float)t1[i], acc[i]);
      }
    }
    p += navail;
  }

  // merge the 8 row-groups (lanes differing in bits 3..5)
#pragma unroll
  for (int i = 0; i < 8; i++) {
    acc[i] += __shfl_xor(acc[i], 8);
    acc[i] += __shfl_xor(acc[i], 16);
    acc[i] += __shfl_xor(acc[i], 32);
  }

  if (r == 0) {
    float4 o0, o1;
    float ov[8];
#pragma unroll
    for (int i = 0; i < 8; i++) ov[i] = fmaf(dv, acc[i], bias[c * 8 + i]);
    o0.x = ov[0]; o0.y = ov[1]; o0.z = ov[2]; o0.w = ov[3];
    o1.x = ov[4]; o1.y = ov[5]; o1.z = ov[6]; o1.w = ov[7];
    *(float4*)&out[(size_t)v * 64 + c * 8]     = o0;
    *(float4*)&out[(size_t)v * 64 + c * 8 + 4] = o1;
  }
}

// ---------------- launch ----------------

extern "C" void kernel_launch(void* const* d_in, const int* in_sizes, int n_in,
                              void* d_out, int out_size, void* d_ws, size_t ws_size,
                              hipStream_t stream) {
  const float* x  = (const float*)d_in[0];
  const int*   ei = (const int*)d_in[1];
  const float* W1 = (const float*)d_in[2];
  const float* b1 = (const float*)d_in[3];
  const float* W2 = (const float*)d_in[4];
  const float* b2 = (const float*)d_in[5];
  const float* W3 = (const float*)d_in[6];
  const float* b3 = (const float*)d_in[7];
  float* outp = (float*)d_out;

  const int N = in_sizes[0] / IN_DIM;   // 100000
  const int E = in_sizes[1] / 2;        // 3200000
  const int* src = ei;
  const int* dst = ei + E;

  char* w = (char*)d_ws;
  auto take = [&](size_t bytes) {
    char* r = w;
    w += (bytes + 255) & ~size_t(255);
    return r;
  };
  float*  dis    = (float*)take((size_t)N * 4);
  int*    rowbeg = (int*)take((size_t)N * 4);
  int*    cur    = (int*)take((size_t)N * 4);
  int*    deg    = (int*)take((size_t)(N + 1) * 4);  // deg[N] = tot counter
  int*    col    = (int*)take((size_t)E * 4);
  _Float16* Wp1  = (_Float16*)take((size_t)IN_DIM * HID_DIM * 2);
  _Float16* Wp2  = (_Float16*)take((size_t)HID_DIM * HID_DIM * 2);
  _Float16* Wp3  = (_Float16*)take((size_t)HID_DIM * OUT_DIM * 2);
  __half* gbuf   = (__half*)take((size_t)N * 128 * 2);  // GEMM out / gather buffer
  __half* bufH   = (__half*)take((size_t)N * 128 * 2);  // agg out (next GEMM A)

  // CSR via direct scatter
  hipMemsetAsync(deg, 0, (size_t)(N + 1) * 4, stream);
  hipLaunchKernelGGL(k_deg, dim3(2048), dim3(256), 0, stream, dst, E, deg);
  hipLaunchKernelGGL(k_alloc, dim3((N + 255) / 256), dim3(256), 0, stream, deg, N, deg + N, rowbeg, cur, dis);
  hipLaunchKernelGGL(k_scat, dim3(2048), dim3(256), 0, stream, src, dst, E, cur, col);

  hipLaunchKernelGGL(k_packAll, dim3((IN_DIM * HID_DIM + HID_DIM * HID_DIM + HID_DIM * OUT_DIM + 255) / 256),
                     dim3(256), 0, stream, W1, Wp1, W2, Wp2, W3, Wp3);

  const int gb = (N + 63) / 64;
  const int ab = (N + 3) / 4;
  const int nh = (N + 1) / 2;               // half-node split for agg128
  const int ab1 = (nh + 3) / 4;
  const int ab2 = (N - nh + 3) / 4;
  // layer 1: gbuf = fp16(dis*(x@W1)) -> agg+relu (two half dispatches) -> bufH
  hipLaunchKernelGGL((k_gemm_mfma<IN_DIM, HID_DIM, float>), dim3(gb), dim3(256), 0, stream, x, Wp1, dis, gbuf, N);
  hipLaunchKernelGGL((k_agg128<true>), dim3(ab1), dim3(256), 0, stream, gbuf, rowbeg, deg, col, dis, b1, bufH, N, 0);
  hipLaunchKernelGGL((k_agg128<true>), dim3(ab2), dim3(256), 0, stream, gbuf, rowbeg, deg, col, dis, b1, bufH, N, nh);
  // layer 2
  hipLaunchKernelGGL((k_gemm_mfma<HID_DIM, HID_DIM, __half>), dim3(gb), dim3(256), 0, stream, bufH, Wp2, dis, gbuf, N);
  hipLaunchKernelGGL((k_agg128<true>), dim3(ab1), dim3(256), 0, stream, gbuf, rowbeg, deg, col, dis, b2, bufH, N, 0);
  hipLaunchKernelGGL((k_agg128<true>), dim3(ab2), dim3(256), 0, stream, gbuf, rowbeg, deg, col, dis, b2, bufH, N, nh);
  // layer 3 (no relu), 64-dim, fp32 straight to d_out
  hipLaunchKernelGGL((k_gemm_mfma<HID_DIM, OUT_DIM, __half>), dim3(gb), dim3(256), 0, stream, bufH, Wp3, dis, gbuf, N);
  hipLaunchKernelGGL(k_agg64, dim3(ab), dim3(256), 0, stream, gbuf, rowbeg, deg, col, dis, b3, outp, N);
}